// Round 2
// baseline (557.776 us; speedup 1.0000x reference)
//
#include <hip/hip_runtime.h>
#include <stdint.h>
#include <stddef.h>

#define HIDDEN 2048
#define INTER  5632
#define TOKENS 4096   // B*S = 2*2048
#define BK     32

typedef __attribute__((ext_vector_type(8)))  _Float16 f16x8;
typedef __attribute__((ext_vector_type(4)))  _Float16 f16x4;
typedef __attribute__((ext_vector_type(16))) float    f32x16;

// LDS tile layout: 128 rows x 32 k (f16). Row = 64B = 4 segments of 16B.
// XOR swizzle: global (row, seg q) lives at slot row*4 + (q ^ (row&3)).
// This makes same-lq / even-row fragment reads alias at most 2-way (free, m136)
// instead of 4-way. Staging side compensates by permuting the GLOBAL segment
// (global_load_lds dst is pinned to base + lane*16, so LDS slots stay linear).
__device__ __forceinline__ int lds_off(int row, int q) {
    return (row * 4 + (q ^ (row & 3))) * 8;   // f16 element index
}

// ---------------------------------------------------------------------------
// fused fp32 -> fp16 conversion of all 4 tensors (1 launch instead of 4)
// ---------------------------------------------------------------------------
__global__ void cvt_all(const float4* __restrict__ x,  const float4* __restrict__ gw,
                        const float4* __restrict__ uw, const float4* __restrict__ dw,
                        f16x4* __restrict__ xo, f16x4* __restrict__ go,
                        f16x4* __restrict__ uo, f16x4* __restrict__ dno) {
    const int NX = TOKENS * HIDDEN / 4;   // 2,097,152
    const int NW = INTER * HIDDEN / 4;    // 2,883,584
    const int total = NX + 3 * NW;
    int i = blockIdx.x * blockDim.x + threadIdx.x;
    const int stride = gridDim.x * blockDim.x;
    for (; i < total; i += stride) {
        const float4* s; f16x4* d; int j;
        if (i < NX)              { s = x;  d = xo;  j = i; }
        else if (i < NX + NW)    { s = gw; d = go;  j = i - NX; }
        else if (i < NX + 2*NW)  { s = uw; d = uo;  j = i - NX - NW; }
        else                     { s = dw; d = dno; j = i - NX - 2*NW; }
        float4 f = s[j];
        f16x4 o;
        o.x = (_Float16)f.x; o.y = (_Float16)f.y;
        o.z = (_Float16)f.z; o.w = (_Float16)f.w;
        d[j] = o;
    }
}

// ---------------------------------------------------------------------------
// GEMM1 fused: G = X*Wg^T, U = X*Wu^T, H = silu(G*gs)*(U*us)  (fp16 out)
// 128x128 tile, BK=32, mfma_f32_32x32x16_f16 (2x2 32-tiles per 64x64 wave)
// ---------------------------------------------------------------------------
__global__ __launch_bounds__(256, 2)
void gemm_gateup(const _Float16* __restrict__ X,
                 const _Float16* __restrict__ Wg,
                 const _Float16* __restrict__ Wu,
                 const float* __restrict__ gs,
                 const float* __restrict__ us,
                 _Float16* __restrict__ Hm) {
    __shared__ _Float16 As [128 * BK];
    __shared__ _Float16 Bgs[128 * BK];
    __shared__ _Float16 Bus[128 * BK];

    const int tid  = threadIdx.x;
    const int lane = tid & 63;
    const int wave = tid >> 6;
    const int wm   = (wave >> 1) * 64;   // wave grid 2x2, 64x64 per wave
    const int wn   = (wave & 1) * 64;
    const int bm   = blockIdx.y * 128;
    const int bn   = blockIdx.x * 128;
    const int l31  = lane & 31;
    const int hi   = lane >> 5;          // 0..1

    // staging: 512 16B-slots per tile, 256 threads -> 2 slots each.
    // thread's LDS slot f is linear; global segment is XOR-permuted.
    const int f0 = tid,      f1 = tid + 256;
    const int row0 = f0 >> 2, row1 = f1 >> 2;
    const int sg0 = ((f0 & 3) ^ (row0 & 3)) * 8;
    const int sg1 = ((f1 & 3) ^ (row1 & 3)) * 8;

    const _Float16* gX0 = X  + (size_t)(bm + row0) * HIDDEN + sg0;
    const _Float16* gX1 = X  + (size_t)(bm + row1) * HIDDEN + sg1;
    const _Float16* gG0 = Wg + (size_t)(bn + row0) * HIDDEN + sg0;
    const _Float16* gG1 = Wg + (size_t)(bn + row1) * HIDDEN + sg1;
    const _Float16* gU0 = Wu + (size_t)(bn + row0) * HIDDEN + sg0;
    const _Float16* gU1 = Wu + (size_t)(bn + row1) * HIDDEN + sg1;

    f32x16 accg[2][2] = {};
    f32x16 accu[2][2] = {};

    for (int k0 = 0; k0 < HIDDEN; k0 += BK) {
        __builtin_amdgcn_global_load_lds(
            (__attribute__((address_space(1))) void*)(gX0 + k0),
            (__attribute__((address_space(3))) void*)&As[f0 * 8], 16, 0, 0);
        __builtin_amdgcn_global_load_lds(
            (__attribute__((address_space(1))) void*)(gX1 + k0),
            (__attribute__((address_space(3))) void*)&As[f1 * 8], 16, 0, 0);
        __builtin_amdgcn_global_load_lds(
            (__attribute__((address_space(1))) void*)(gG0 + k0),
            (__attribute__((address_space(3))) void*)&Bgs[f0 * 8], 16, 0, 0);
        __builtin_amdgcn_global_load_lds(
            (__attribute__((address_space(1))) void*)(gG1 + k0),
            (__attribute__((address_space(3))) void*)&Bgs[f1 * 8], 16, 0, 0);
        __builtin_amdgcn_global_load_lds(
            (__attribute__((address_space(1))) void*)(gU0 + k0),
            (__attribute__((address_space(3))) void*)&Bus[f0 * 8], 16, 0, 0);
        __builtin_amdgcn_global_load_lds(
            (__attribute__((address_space(1))) void*)(gU1 + k0),
            (__attribute__((address_space(3))) void*)&Bus[f1 * 8], 16, 0, 0);
        __syncthreads();

        #pragma unroll
        for (int ks = 0; ks < 2; ++ks) {
            const int q = ks * 2 + hi;   // 16B segment for this MFMA's K-slice
            f16x8 a0 = *(const f16x8*)&As [lds_off(wm      + l31, q)];
            f16x8 a1 = *(const f16x8*)&As [lds_off(wm + 32 + l31, q)];
            f16x8 g0 = *(const f16x8*)&Bgs[lds_off(wn      + l31, q)];
            f16x8 g1 = *(const f16x8*)&Bgs[lds_off(wn + 32 + l31, q)];
            f16x8 u0 = *(const f16x8*)&Bus[lds_off(wn      + l31, q)];
            f16x8 u1 = *(const f16x8*)&Bus[lds_off(wn + 32 + l31, q)];
            accg[0][0] = __builtin_amdgcn_mfma_f32_32x32x16_f16(a0, g0, accg[0][0], 0, 0, 0);
            accg[0][1] = __builtin_amdgcn_mfma_f32_32x32x16_f16(a0, g1, accg[0][1], 0, 0, 0);
            accg[1][0] = __builtin_amdgcn_mfma_f32_32x32x16_f16(a1, g0, accg[1][0], 0, 0, 0);
            accg[1][1] = __builtin_amdgcn_mfma_f32_32x32x16_f16(a1, g1, accg[1][1], 0, 0, 0);
            accu[0][0] = __builtin_amdgcn_mfma_f32_32x32x16_f16(a0, u0, accu[0][0], 0, 0, 0);
            accu[0][1] = __builtin_amdgcn_mfma_f32_32x32x16_f16(a0, u1, accu[0][1], 0, 0, 0);
            accu[1][0] = __builtin_amdgcn_mfma_f32_32x32x16_f16(a1, u0, accu[1][0], 0, 0, 0);
            accu[1][1] = __builtin_amdgcn_mfma_f32_32x32x16_f16(a1, u1, accu[1][1], 0, 0, 0);
        }
        __syncthreads();
    }

    // epilogue: 32x32 C/D layout col = lane&31, row = (reg&3)+8*(reg>>2)+4*(lane>>5)
    #pragma unroll
    for (int jn = 0; jn < 2; ++jn) {
        const int col = bn + wn + jn * 32 + l31;
        const float sg = gs[col];
        const float su = us[col];
        #pragma unroll
        for (int im = 0; im < 2; ++im) {
            const int rbase = bm + wm + im * 32 + hi * 4;
            #pragma unroll
            for (int r = 0; r < 16; ++r) {
                const int row = rbase + (r & 3) + 8 * (r >> 2);
                float g = accg[im][jn][r] * sg;
                float u = accu[im][jn][r] * su;
                float h = (g / (1.0f + __expf(-g))) * u;   // silu(g)*u
                Hm[(size_t)row * INTER + col] = (_Float16)h;
            }
        }
    }
}

// ---------------------------------------------------------------------------
// GEMM2: out = (H @ Wd^T) * down_s    (fp32 out), K = INTER
// ---------------------------------------------------------------------------
__global__ __launch_bounds__(256, 2)
void gemm_down(const _Float16* __restrict__ Hm,
               const _Float16* __restrict__ Wd,
               const float* __restrict__ dsc,
               float* __restrict__ out) {
    __shared__ _Float16 As[128 * BK];
    __shared__ _Float16 Bs[128 * BK];

    const int tid  = threadIdx.x;
    const int lane = tid & 63;
    const int wave = tid >> 6;
    const int wm   = (wave >> 1) * 64;
    const int wn   = (wave & 1) * 64;
    const int bm   = blockIdx.y * 128;
    const int bn   = blockIdx.x * 128;
    const int l31  = lane & 31;
    const int hi   = lane >> 5;

    const int f0 = tid,      f1 = tid + 256;
    const int row0 = f0 >> 2, row1 = f1 >> 2;
    const int sg0 = ((f0 & 3) ^ (row0 & 3)) * 8;
    const int sg1 = ((f1 & 3) ^ (row1 & 3)) * 8;

    const _Float16* gA0 = Hm + (size_t)(bm + row0) * INTER + sg0;
    const _Float16* gA1 = Hm + (size_t)(bm + row1) * INTER + sg1;
    const _Float16* gB0 = Wd + (size_t)(bn + row0) * INTER + sg0;
    const _Float16* gB1 = Wd + (size_t)(bn + row1) * INTER + sg1;

    f32x16 acc[2][2] = {};

    for (int k0 = 0; k0 < INTER; k0 += BK) {
        __builtin_amdgcn_global_load_lds(
            (__attribute__((address_space(1))) void*)(gA0 + k0),
            (__attribute__((address_space(3))) void*)&As[f0 * 8], 16, 0, 0);
        __builtin_amdgcn_global_load_lds(
            (__attribute__((address_space(1))) void*)(gA1 + k0),
            (__attribute__((address_space(3))) void*)&As[f1 * 8], 16, 0, 0);
        __builtin_amdgcn_global_load_lds(
            (__attribute__((address_space(1))) void*)(gB0 + k0),
            (__attribute__((address_space(3))) void*)&Bs[f0 * 8], 16, 0, 0);
        __builtin_amdgcn_global_load_lds(
            (__attribute__((address_space(1))) void*)(gB1 + k0),
            (__attribute__((address_space(3))) void*)&Bs[f1 * 8], 16, 0, 0);
        __syncthreads();

        #pragma unroll
        for (int ks = 0; ks < 2; ++ks) {
            const int q = ks * 2 + hi;
            f16x8 a0 = *(const f16x8*)&As[lds_off(wm      + l31, q)];
            f16x8 a1 = *(const f16x8*)&As[lds_off(wm + 32 + l31, q)];
            f16x8 b0 = *(const f16x8*)&Bs[lds_off(wn      + l31, q)];
            f16x8 b1 = *(const f16x8*)&Bs[lds_off(wn + 32 + l31, q)];
            acc[0][0] = __builtin_amdgcn_mfma_f32_32x32x16_f16(a0, b0, acc[0][0], 0, 0, 0);
            acc[0][1] = __builtin_amdgcn_mfma_f32_32x32x16_f16(a0, b1, acc[0][1], 0, 0, 0);
            acc[1][0] = __builtin_amdgcn_mfma_f32_32x32x16_f16(a1, b0, acc[1][0], 0, 0, 0);
            acc[1][1] = __builtin_amdgcn_mfma_f32_32x32x16_f16(a1, b1, acc[1][1], 0, 0, 0);
        }
        __syncthreads();
    }

    #pragma unroll
    for (int jn = 0; jn < 2; ++jn) {
        const int col = bn + wn + jn * 32 + l31;
        const float sd = dsc[col];
        #pragma unroll
        for (int im = 0; im < 2; ++im) {
            const int rbase = bm + wm + im * 32 + hi * 4;
            #pragma unroll
            for (int r = 0; r < 16; ++r) {
                const int row = rbase + (r & 3) + 8 * (r >> 2);
                out[(size_t)row * HIDDEN + col] = acc[im][jn][r] * sd;
            }
        }
    }
}

// ---------------------------------------------------------------------------
// launch
// ---------------------------------------------------------------------------
extern "C" void kernel_launch(void* const* d_in, const int* in_sizes, int n_in,
                              void* d_out, int out_size, void* d_ws, size_t ws_size,
                              hipStream_t stream) {
    const float* x   = (const float*)d_in[0];
    const float* gw  = (const float*)d_in[1];
    const float* uw  = (const float*)d_in[2];
    const float* dw  = (const float*)d_in[3];
    const float* gsc = (const float*)d_in[4];
    const float* usc = (const float*)d_in[5];
    const float* dsc = (const float*)d_in[6];
    float* out = (float*)d_out;

    char* ws = (char*)d_ws;
    _Float16* Xh  = (_Float16*)(ws);
    _Float16* Wgh = (_Float16*)(ws + 16777216ull);
    _Float16* Wuh = (_Float16*)(ws + 39845888ull);
    _Float16* Wdh = (_Float16*)(ws + 62914560ull);
    _Float16* Hm  = (_Float16*)(ws + 85983232ull);

    cvt_all<<<2048, 256, 0, stream>>>((const float4*)x,  (const float4*)gw,
                                      (const float4*)uw, (const float4*)dw,
                                      (f16x4*)Xh, (f16x4*)Wgh, (f16x4*)Wuh, (f16x4*)Wdh);

    gemm_gateup<<<dim3(INTER / 128, TOKENS / 128), 256, 0, stream>>>(
        Xh, Wgh, Wuh, gsc, usc, Hm);
    gemm_down<<<dim3(HIDDEN / 128, TOKENS / 128), 256, 0, stream>>>(
        Hm, Wdh, dsc, out);
}

// Round 3
// 418.816 us; speedup vs baseline: 1.3318x; 1.3318x over previous
//
#include <hip/hip_runtime.h>
#include <stdint.h>
#include <stddef.h>

#define HIDDEN 2048
#define INTER  5632
#define TOKENS 4096   // B*S = 2*2048
#define BK     32     // f16 K-tile (down GEMM)
#define BKI    64     // i8 K-tile (gateup GEMM) -- same 64B/row as f16 BK=32

typedef __attribute__((ext_vector_type(8))) _Float16 f16x8;
typedef __attribute__((ext_vector_type(4))) _Float16 f16x4;
typedef __attribute__((ext_vector_type(4))) float    f32x4;
typedef __attribute__((ext_vector_type(4))) int      i32x4;

// ---------------------------------------------------------------------------
// per-token dynamic i8 quantization of x: one block per token (2048 floats)
// writes xq (i8) and xs[t] = absmax/127 (the dequant scale)
// ---------------------------------------------------------------------------
__global__ __launch_bounds__(256)
void quant_x(const float* __restrict__ x, int8_t* __restrict__ xq,
             float* __restrict__ xs) {
    const int t   = blockIdx.x;
    const int tid = threadIdx.x;
    const float4* row = (const float4*)(x + (size_t)t * HIDDEN);
    float4 v0 = row[tid * 2];
    float4 v1 = row[tid * 2 + 1];
    float m = fmaxf(fmaxf(fabsf(v0.x), fabsf(v0.y)), fmaxf(fabsf(v0.z), fabsf(v0.w)));
    m = fmaxf(m, fmaxf(fmaxf(fabsf(v1.x), fabsf(v1.y)), fmaxf(fabsf(v1.z), fabsf(v1.w))));
    #pragma unroll
    for (int off = 32; off; off >>= 1)
        m = fmaxf(m, __shfl_xor(m, off, 64));
    __shared__ float wmax[4];
    if ((tid & 63) == 0) wmax[tid >> 6] = m;
    __syncthreads();
    m = fmaxf(fmaxf(wmax[0], wmax[1]), fmaxf(wmax[2], wmax[3]));
    m = fmaxf(m, 1e-20f);
    if (tid == 0) xs[t] = m * (1.0f / 127.0f);
    const float inv = 127.0f / m;
    float vals[8] = {v0.x, v0.y, v0.z, v0.w, v1.x, v1.y, v1.z, v1.w};
    int b[8];
    #pragma unroll
    for (int i = 0; i < 8; ++i) b[i] = (int)rintf(vals[i] * inv);
    int lo = (b[0] & 255) | ((b[1] & 255) << 8) | ((b[2] & 255) << 16) | (b[3] << 24);
    int hi = (b[4] & 255) | ((b[5] & 255) << 8) | ((b[6] & 255) << 16) | (b[7] << 24);
    ((int2*)(xq + (size_t)t * HIDDEN))[tid] = make_int2(lo, hi);
}

// ---------------------------------------------------------------------------
// weight conversion: gate/up fp32 {-1,0,1} -> i8 exact; down fp32 -> f16 exact
// ---------------------------------------------------------------------------
__global__ void cvt_w(const float4* __restrict__ gw, const float4* __restrict__ uw,
                      const float4* __restrict__ dw,
                      int* __restrict__ go, int* __restrict__ uo,
                      f16x4* __restrict__ dno) {
    const int NW4 = INTER * HIDDEN / 4;   // 2,883,584
    int i = blockIdx.x * blockDim.x + threadIdx.x;
    const int stride = gridDim.x * blockDim.x;
    for (; i < 3 * NW4; i += stride) {
        if (i < 2 * NW4) {
            const bool is_g = i < NW4;
            const int j = is_g ? i : i - NW4;
            float4 f = is_g ? gw[j] : uw[j];
            int p = ((int)(signed char)(int)f.x & 255)
                  | (((int)(signed char)(int)f.y & 255) << 8)
                  | (((int)(signed char)(int)f.z & 255) << 16)
                  | (((int)(signed char)(int)f.w) << 24);
            if (is_g) go[j] = p; else uo[j] = p;
        } else {
            const int j = i - 2 * NW4;
            float4 f = dw[j];
            f16x4 o;
            o.x = (_Float16)f.x; o.y = (_Float16)f.y;
            o.z = (_Float16)f.z; o.w = (_Float16)f.w;
            dno[j] = o;
        }
    }
}

// ---------------------------------------------------------------------------
// GEMM1 fused (i8): G = Xq*Wg^T, U = Xq*Wu^T (exact int32), then
// H = silu(G*xs*gs) * (U*xs*us)  (fp16 out)
// Round-1 skeleton: 128x128 tile, 64B LDS rows, linear slots,
// mfma_i32_16x16x64_i8 (K=64 = whole tile per instruction)
// ---------------------------------------------------------------------------
__global__ __launch_bounds__(256, 2)
void gemm_gateup(const int8_t* __restrict__ Xq,
                 const int8_t* __restrict__ Wg,
                 const int8_t* __restrict__ Wu,
                 const float* __restrict__ xs,
                 const float* __restrict__ gs,
                 const float* __restrict__ us,
                 _Float16* __restrict__ Hm) {
    __shared__ int8_t As [128 * BKI];
    __shared__ int8_t Bgs[128 * BKI];
    __shared__ int8_t Bus[128 * BKI];

    const int tid  = threadIdx.x;
    const int lane = tid & 63;
    const int wave = tid >> 6;
    const int wm   = (wave >> 1) * 64;   // wave grid 2x2, 64x64 per wave
    const int wn   = (wave & 1) * 64;
    const int bm   = blockIdx.y * 128;
    const int bn   = blockIdx.x * 128;
    const int l15  = lane & 15;
    const int lq   = lane >> 4;          // 0..3

    // staging: tile = 128 rows x 64B = 512 x 16B slots; 256 threads x 2
    const int f0 = tid,       f1 = tid + 256;
    const int row0 = f0 >> 2, row1 = f1 >> 2;
    const int sg0 = (f0 & 3) * 16, sg1 = (f1 & 3) * 16;

    const int8_t* gX0 = Xq + (size_t)(bm + row0) * HIDDEN + sg0;
    const int8_t* gX1 = Xq + (size_t)(bm + row1) * HIDDEN + sg1;
    const int8_t* gG0 = Wg + (size_t)(bn + row0) * HIDDEN + sg0;
    const int8_t* gG1 = Wg + (size_t)(bn + row1) * HIDDEN + sg1;
    const int8_t* gU0 = Wu + (size_t)(bn + row0) * HIDDEN + sg0;
    const int8_t* gU1 = Wu + (size_t)(bn + row1) * HIDDEN + sg1;

    i32x4 accg[4][4] = {};
    i32x4 accu[4][4] = {};

    for (int k0 = 0; k0 < HIDDEN; k0 += BKI) {
        __builtin_amdgcn_global_load_lds(
            (__attribute__((address_space(1))) void*)(gX0 + k0),
            (__attribute__((address_space(3))) void*)&As[f0 * 16], 16, 0, 0);
        __builtin_amdgcn_global_load_lds(
            (__attribute__((address_space(1))) void*)(gX1 + k0),
            (__attribute__((address_space(3))) void*)&As[f1 * 16], 16, 0, 0);
        __builtin_amdgcn_global_load_lds(
            (__attribute__((address_space(1))) void*)(gG0 + k0),
            (__attribute__((address_space(3))) void*)&Bgs[f0 * 16], 16, 0, 0);
        __builtin_amdgcn_global_load_lds(
            (__attribute__((address_space(1))) void*)(gG1 + k0),
            (__attribute__((address_space(3))) void*)&Bgs[f1 * 16], 16, 0, 0);
        __builtin_amdgcn_global_load_lds(
            (__attribute__((address_space(1))) void*)(gU0 + k0),
            (__attribute__((address_space(3))) void*)&Bus[f0 * 16], 16, 0, 0);
        __builtin_amdgcn_global_load_lds(
            (__attribute__((address_space(1))) void*)(gU1 + k0),
            (__attribute__((address_space(3))) void*)&Bus[f1 * 16], 16, 0, 0);
        __syncthreads();

        // fragment: A[m = l15][k = lq*16 + j], 16 i8 = one b128 read
        i32x4 a[4];
        #pragma unroll
        for (int im = 0; im < 4; ++im)
            a[im] = *(const i32x4*)&As[(wm + im * 16 + l15) * BKI + lq * 16];
        #pragma unroll
        for (int jn = 0; jn < 4; ++jn) {
            i32x4 bg = *(const i32x4*)&Bgs[(wn + jn * 16 + l15) * BKI + lq * 16];
            i32x4 bu = *(const i32x4*)&Bus[(wn + jn * 16 + l15) * BKI + lq * 16];
            #pragma unroll
            for (int im = 0; im < 4; ++im) {
                accg[im][jn] = __builtin_amdgcn_mfma_i32_16x16x64_i8(a[im], bg, accg[im][jn], 0, 0, 0);
                accu[im][jn] = __builtin_amdgcn_mfma_i32_16x16x64_i8(a[im], bu, accu[im][jn], 0, 0, 0);
            }
        }
        __syncthreads();
    }

    // epilogue: C/D layout col = lane&15, row = lq*4 + reg  [m89]
    #pragma unroll
    for (int jn = 0; jn < 4; ++jn) {
        const int col = bn + wn + jn * 16 + l15;
        const float sg = gs[col];
        const float su = us[col];
        #pragma unroll
        for (int im = 0; im < 4; ++im) {
            const int rbase = bm + wm + im * 16 + lq * 4;
            #pragma unroll
            for (int r = 0; r < 4; ++r) {
                const int row = rbase + r;
                const float st = xs[row];   // per-token dequant scale
                float g = (float)accg[im][jn][r] * st * sg;
                float u = (float)accu[im][jn][r] * st * su;
                float h = (g / (1.0f + __expf(-g))) * u;   // silu(g)*u
                Hm[(size_t)row * INTER + col] = (_Float16)h;
            }
        }
    }
}

// ---------------------------------------------------------------------------
// GEMM2 (fp16, round-1 verbatim): out = (H @ Wd^T) * down_s   (fp32 out)
// ---------------------------------------------------------------------------
__global__ __launch_bounds__(256, 2)
void gemm_down(const _Float16* __restrict__ Hm,
               const _Float16* __restrict__ Wd,
               const float* __restrict__ dsc,
               float* __restrict__ out) {
    __shared__ _Float16 As[128 * BK];
    __shared__ _Float16 Bs[128 * BK];

    const int tid  = threadIdx.x;
    const int lane = tid & 63;
    const int wave = tid >> 6;
    const int wm   = (wave >> 1) * 64;
    const int wn   = (wave & 1) * 64;
    const int bm   = blockIdx.y * 128;
    const int bn   = blockIdx.x * 128;
    const int l15  = lane & 15;
    const int lq   = lane >> 4;

    const int f0 = tid,       f1 = tid + 256;
    const int row0 = f0 >> 2, row1 = f1 >> 2;
    const int sg0 = (f0 & 3) * 8, sg1 = (f1 & 3) * 8;

    const _Float16* gA0 = Hm + (size_t)(bm + row0) * INTER + sg0;
    const _Float16* gA1 = Hm + (size_t)(bm + row1) * INTER + sg1;
    const _Float16* gB0 = Wd + (size_t)(bn + row0) * INTER + sg0;
    const _Float16* gB1 = Wd + (size_t)(bn + row1) * INTER + sg1;

    f32x4 acc[4][4] = {};

    for (int k0 = 0; k0 < INTER; k0 += BK) {
        __builtin_amdgcn_global_load_lds(
            (__attribute__((address_space(1))) void*)(gA0 + k0),
            (__attribute__((address_space(3))) void*)&As[f0 * 8], 16, 0, 0);
        __builtin_amdgcn_global_load_lds(
            (__attribute__((address_space(1))) void*)(gA1 + k0),
            (__attribute__((address_space(3))) void*)&As[f1 * 8], 16, 0, 0);
        __builtin_amdgcn_global_load_lds(
            (__attribute__((address_space(1))) void*)(gB0 + k0),
            (__attribute__((address_space(3))) void*)&Bs[f0 * 8], 16, 0, 0);
        __builtin_amdgcn_global_load_lds(
            (__attribute__((address_space(1))) void*)(gB1 + k0),
            (__attribute__((address_space(3))) void*)&Bs[f1 * 8], 16, 0, 0);
        __syncthreads();

        f16x8 a[4];
        #pragma unroll
        for (int im = 0; im < 4; ++im)
            a[im] = *(const f16x8*)&As[(wm + im * 16 + l15) * BK + lq * 8];
        #pragma unroll
        for (int jn = 0; jn < 4; ++jn) {
            f16x8 b = *(const f16x8*)&Bs[(wn + jn * 16 + l15) * BK + lq * 8];
            #pragma unroll
            for (int im = 0; im < 4; ++im)
                acc[im][jn] = __builtin_amdgcn_mfma_f32_16x16x32_f16(a[im], b, acc[im][jn], 0, 0, 0);
        }
        __syncthreads();
    }

    #pragma unroll
    for (int jn = 0; jn < 4; ++jn) {
        const int col = bn + wn + jn * 16 + l15;
        const float sd = dsc[col];
        #pragma unroll
        for (int im = 0; im < 4; ++im) {
            const int rbase = bm + wm + im * 16 + lq * 4;
            #pragma unroll
            for (int r = 0; r < 4; ++r)
                out[(size_t)(rbase + r) * HIDDEN + col] = acc[im][jn][r] * sd;
        }
    }
}

// ---------------------------------------------------------------------------
// launch
// ---------------------------------------------------------------------------
extern "C" void kernel_launch(void* const* d_in, const int* in_sizes, int n_in,
                              void* d_out, int out_size, void* d_ws, size_t ws_size,
                              hipStream_t stream) {
    const float* x   = (const float*)d_in[0];
    const float* gw  = (const float*)d_in[1];
    const float* uw  = (const float*)d_in[2];
    const float* dw  = (const float*)d_in[3];
    const float* gsc = (const float*)d_in[4];
    const float* usc = (const float*)d_in[5];
    const float* dsc = (const float*)d_in[6];
    float* out = (float*)d_out;

    // workspace layout:
    //   Xq  i8  : 8,388,608
    //   Wg8 i8  : 11,534,336   @  8,388,608
    //   Wu8 i8  : 11,534,336   @ 19,922,944
    //   Wdh f16 : 23,068,672   @ 31,457,280
    //   Hm  f16 : 46,137,344   @ 54,525,952
    //   xs  f32 :     16,384   @100,663,296     total ~100.7 MB
    char* ws = (char*)d_ws;
    int8_t*   Xq  = (int8_t*)(ws);
    int8_t*   Wg8 = (int8_t*)(ws + 8388608ull);
    int8_t*   Wu8 = (int8_t*)(ws + 19922944ull);
    _Float16* Wdh = (_Float16*)(ws + 31457280ull);
    _Float16* Hm  = (_Float16*)(ws + 54525952ull);
    float*    xs  = (float*)(ws + 100663296ull);

    quant_x<<<TOKENS, 256, 0, stream>>>(x, Xq, xs);
    cvt_w<<<2048, 256, 0, stream>>>((const float4*)gw, (const float4*)uw,
                                    (const float4*)dw,
                                    (int*)Wg8, (int*)Wu8, (f16x4*)Wdh);

    gemm_gateup<<<dim3(INTER / 128, TOKENS / 128), 256, 0, stream>>>(
        Xq, Wg8, Wu8, xs, gsc, usc, Hm);
    gemm_down<<<dim3(HIDDEN / 128, TOKENS / 128), 256, 0, stream>>>(
        Hm, Wdh, dsc, out);
}